// Round 9
// baseline (512.323 us; speedup 1.0000x reference)
//
#include <hip/hip_runtime.h>

typedef __bf16 bf16x8 __attribute__((ext_vector_type(8)));
typedef float  f32x4  __attribute__((ext_vector_type(4)));
typedef float  f32x2  __attribute__((ext_vector_type(2)));

#define NNODES   50000
#define DIN      256
#define HEADS    32
#define CDIM     16
#define NH       512          // HEADS*CDIM
#define ERAW     800000
#define SCAN_B   196          // ceil(50000/256)
#define LDSW     280          // padded A-row in bf16: 2-way bank alias (free)

__device__ __forceinline__ float b2f(unsigned short u) {
    return __uint_as_float(((unsigned)u) << 16);
}
__device__ __forceinline__ unsigned short f2b(float f) {
    unsigned v = __float_as_uint(f);
    v += 0x7fffu + ((v >> 16) & 1u);           // RNE
    return (unsigned short)(v >> 16);
}

// zero degree array + probe edge_index width (int64 -> odd slots all zero)
__global__ void k_prep(const int* __restrict__ ei, int* __restrict__ flag,
                       int* __restrict__ deg) {
    int i = blockIdx.x * 256 + threadIdx.x;
    if (i < NNODES) deg[i] = 0;
    if (i == 0) {
        int nz = 0;
        #pragma unroll
        for (int t = 0; t < 64; ++t) nz |= ei[2 * t + 1];
        flag[0] = (nz == 0) ? 1 : 0;           // 1 => int64
    }
}

__global__ void k_hist(const int* __restrict__ ei, const int* __restrict__ flag,
                       int* __restrict__ deg) {
    int e = blockIdx.x * 256 + threadIdx.x;    // exactly 800000
    int d = flag[0] ? ei[2 * ERAW + 2 * e] : ei[ERAW + e];
    atomicAdd(&deg[d], 1);
}

__global__ void k_scan_blk(const int* __restrict__ deg, int* __restrict__ part,
                           int* __restrict__ bsum) {
    __shared__ int sm[256];
    int b = blockIdx.x, t = threadIdx.x, i = b * 256 + t;
    int v = (i < NNODES) ? deg[i] : 0;
    sm[t] = v; __syncthreads();
    for (int off = 1; off < 256; off <<= 1) {
        int u = (t >= off) ? sm[t - off] : 0;
        __syncthreads();
        sm[t] += u; __syncthreads();
    }
    if (i < NNODES) part[i] = sm[t] - v;
    if (t == 255) bsum[b] = sm[255];
}

__global__ void k_scan_top(int* __restrict__ bsum) {
    __shared__ int sm[256];
    int t = threadIdx.x;
    int v = (t < SCAN_B) ? bsum[t] : 0;
    sm[t] = v; __syncthreads();
    for (int off = 1; off < 256; off <<= 1) {
        int u = (t >= off) ? sm[t - off] : 0;
        __syncthreads();
        sm[t] += u; __syncthreads();
    }
    if (t < SCAN_B) bsum[t] = sm[t] - v;
}

__global__ void k_scan_add(const int* __restrict__ part, const int* __restrict__ bsum,
                           int* __restrict__ rs, int* __restrict__ cur) {
    int b = blockIdx.x, t = threadIdx.x, i = b * 256 + t;
    if (i < NNODES) { int r = part[i] + bsum[b]; rs[i] = r; cur[i] = r; }
}

__global__ void k_scatter(const int* __restrict__ ei, const int* __restrict__ flag,
                          int* __restrict__ cur, int* __restrict__ csr) {
    int e = blockIdx.x * 256 + threadIdx.x;    // exactly 800000
    int s, d;
    if (flag[0]) { s = ei[2 * e]; d = ei[2 * ERAW + 2 * e]; }
    else         { s = ei[e];     d = ei[ERAW + e]; }
    int pos = atomicAdd(&cur[d], 1);
    csr[pos] = s;
}

// all four weight transposes (fp32 -> bf16), one launch
__global__ void k_trW(const float* __restrict__ W1, const float* __restrict__ W2,
                      const float* __restrict__ w1, const float* __restrict__ w2,
                      unsigned short* __restrict__ Wt1, unsigned short* __restrict__ Wt2,
                      unsigned short* __restrict__ w1t, unsigned short* __restrict__ w2t) {
    int b = blockIdx.x, t = threadIdx.x;
    if (b < 512)            Wt1[b * 256 + t] = f2b(W1[t * 512 + b]);
    else if (b < 1024) { int n = b - 512;  Wt2[n * 256 + t] = f2b(W2[t * 512 + n]); }
    else if (b < 1088) { int n = b - 1024; w1t[n * 256 + t] = f2b(w1[t * 64 + n]); }
    else               { int n = b - 1088; if (t < 64) w2t[n * 64 + t] = f2b(w2[t * 16 + n]); }
}

// xp8 = fp8_e4m3(x @ W), permuted layout: dword at row*128 + w*16 + r packs
// bytes t=0..3 = (head 4w+t, channel r). Block: 64 rows x 512 cols, 8 waves.
// A staged fp32->bf16->LDS inline.
__global__ void __launch_bounds__(512)
k_gemm_xp(const float* __restrict__ x,
          const unsigned short* __restrict__ Wt,
          unsigned* __restrict__ xp8) {
    __shared__ unsigned short As[64 * LDSW];
    int row0 = blockIdx.x * 64;                // 782 blocks
    int tid = threadIdx.x;
    int w = tid >> 6, lane = tid & 63;
    int r = lane & 15, quad = lane >> 4;

    {   // stage: 8 threads/row, each 8 float4 -> 4 uint4 bf16
        int row = tid >> 3, seg = tid & 7;
        int grow = row0 + row;
        uint4* l = (uint4*)(As + row * LDSW);
        if (grow < NNODES) {
            const float4* g = (const float4*)(x + (size_t)grow * DIN);
            #pragma unroll
            for (int i = 0; i < 4; ++i) {
                float4 f0 = g[seg * 8 + 2 * i];
                float4 f1 = g[seg * 8 + 2 * i + 1];
                uint4 o;
                o.x = (unsigned)f2b(f0.x) | ((unsigned)f2b(f0.y) << 16);
                o.y = (unsigned)f2b(f0.z) | ((unsigned)f2b(f0.w) << 16);
                o.z = (unsigned)f2b(f1.x) | ((unsigned)f2b(f1.y) << 16);
                o.w = (unsigned)f2b(f1.z) | ((unsigned)f2b(f1.w) << 16);
                l[seg * 4 + i] = o;
            }
        } else {
            uint4 z = {0, 0, 0, 0};
            #pragma unroll
            for (int i = 0; i < 4; ++i) l[seg * 4 + i] = z;
        }
    }
    __syncthreads();

    f32x4 acc[4][4] = {};
    #pragma unroll
    for (int kc = 0; kc < 8; ++kc) {
        bf16x8 a[4], b[4];
        #pragma unroll
        for (int sub = 0; sub < 4; ++sub)
            a[sub] = *(const bf16x8*)(As + (sub * 16 + r) * LDSW + kc * 32 + quad * 8);
        #pragma unroll
        for (int t = 0; t < 4; ++t) {
            int col = w * 64 + t * 16 + r;
            b[t] = *(const bf16x8*)(Wt + (size_t)col * DIN + kc * 32 + quad * 8);
        }
        #pragma unroll
        for (int t = 0; t < 4; ++t)
            #pragma unroll
            for (int sub = 0; sub < 4; ++sub)
                acc[sub][t] = __builtin_amdgcn_mfma_f32_16x16x32_bf16(a[sub], b[t], acc[sub][t], 0, 0, 0);
    }
    #pragma unroll
    for (int sub = 0; sub < 4; ++sub) {
        #pragma unroll
        for (int j = 0; j < 4; ++j) {
            int row = row0 + sub * 16 + quad * 4 + j;
            if (row < NNODES) {
                unsigned u = (unsigned)__builtin_amdgcn_cvt_pk_fp8_f32(
                                 acc[sub][0][j], acc[sub][1][j], 0, false);
                u = (unsigned)__builtin_amdgcn_cvt_pk_fp8_f32(
                                 acc[sub][2][j], acc[sub][3][j], (int)u, true);
                xp8[(size_t)row * 128 + w * 16 + r] = u;
            }
        }
    }
}

// scores from fp8 payload; outputs bf16. One wave per node.
// lane ln: group g=ln>>3 covers heads 4g..4g+3, channel pair 2m,2m+1 (m=ln&7).
__global__ void k_att(const unsigned* __restrict__ xp8,
                      const float* __restrict__ att_src,
                      const float* __restrict__ att_dst,
                      unsigned short* __restrict__ a_sb, unsigned short* __restrict__ a_db) {
    __shared__ float sS[512], sD[512];
    int tid = threadIdx.x;
    sS[tid] = att_src[tid]; sS[tid + 256] = att_src[tid + 256];
    sD[tid] = att_dst[tid]; sD[tid + 256] = att_dst[tid + 256];
    __syncthreads();
    int nd = blockIdx.x * 4 + (tid >> 6);      // exactly 50000
    int ln = tid & 63;
    int m = ln & 7, g = ln >> 3;

    const uint2 q = *(const uint2*)(xp8 + (size_t)nd * 128 + ln * 2);
    f32x2 p0 = __builtin_amdgcn_cvt_pk_f32_fp8((int)q.x, false);
    f32x2 p1 = __builtin_amdgcn_cvt_pk_f32_fp8((int)q.x, true);
    f32x2 p2 = __builtin_amdgcn_cvt_pk_f32_fp8((int)q.y, false);
    f32x2 p3 = __builtin_amdgcn_cvt_pk_f32_fp8((int)q.y, true);
    float f[8] = {p0.x, p0.y, p1.x, p1.y, p2.x, p2.y, p3.x, p3.y};

    float ps[4], pd[4];
    #pragma unroll
    for (int t = 0; t < 4; ++t) {
        int h = g * 4 + t;
        int c0 = 2 * m, c1 = 2 * m + 1;
        ps[t] = f[t] * sS[h * 16 + c0] + f[4 + t] * sS[h * 16 + c1];
        pd[t] = f[t] * sD[h * 16 + c0] + f[4 + t] * sD[h * 16 + c1];
    }
    #pragma unroll
    for (int mask = 1; mask <= 4; mask <<= 1) {
        #pragma unroll
        for (int t = 0; t < 4; ++t) {
            ps[t] += __shfl_xor(ps[t], mask, 64);
            pd[t] += __shfl_xor(pd[t], mask, 64);
        }
    }
    if (m == 0) {
        uint2 os, od;
        os.x = (unsigned)f2b(ps[0]) | ((unsigned)f2b(ps[1]) << 16);
        os.y = (unsigned)f2b(ps[2]) | ((unsigned)f2b(ps[3]) << 16);
        od.x = (unsigned)f2b(pd[0]) | ((unsigned)f2b(pd[1]) << 16);
        od.y = (unsigned)f2b(pd[2]) | ((unsigned)f2b(pd[3]) << 16);
        *(uint2*)(a_sb + nd * HEADS + 4 * g) = os;
        *(uint2*)(a_db + nd * HEADS + 4 * g) = od;
    }
}

// One wave per dst node; fp8 permuted-payload gather, bf16 scores, fp32 softmax.
__global__ void k_conv(const int* __restrict__ csr, const int* __restrict__ rs,
                       const int* __restrict__ deg,
                       const unsigned* __restrict__ xp8,
                       const unsigned short* __restrict__ a_sb,
                       const unsigned short* __restrict__ a_db,
                       const float* __restrict__ bias, float* __restrict__ out) {
    int nd = blockIdx.x * 4 + (threadIdx.x >> 6);      // exactly 50000
    int ln = threadIdx.x & 63;
    int h0 = ln & 31;                                  // score duty head
    int base = (ln >> 3) * 4;                          // payload heads base
    float adn = b2f(a_db[nd * HEADS + h0]);
    int beg = __builtin_amdgcn_readfirstlane(rs[nd]);
    int cnt = __builtin_amdgcn_readfirstlane(deg[nd]);
    const uint2* xv = (const uint2*)xp8;               // 64 uint2 per row

    float denom = 0.f;
    float acc[8] = {0, 0, 0, 0, 0, 0, 0, 0};

    #define EDGE_BODY(AV, QV)                                              \
    {                                                                      \
        float tt = (AV) + adn;                                             \
        tt = tt > 0.f ? tt : 0.2f * tt;                                    \
        float e = __expf(tt);                                              \
        denom += e;                                                        \
        float es0 = __shfl(e, base + 0, 64);                               \
        float es1 = __shfl(e, base + 1, 64);                               \
        float es2 = __shfl(e, base + 2, 64);                               \
        float es3 = __shfl(e, base + 3, 64);                               \
        f32x2 p0 = __builtin_amdgcn_cvt_pk_f32_fp8((int)(QV).x, false);    \
        f32x2 p1 = __builtin_amdgcn_cvt_pk_f32_fp8((int)(QV).x, true);     \
        f32x2 p2 = __builtin_amdgcn_cvt_pk_f32_fp8((int)(QV).y, false);    \
        f32x2 p3 = __builtin_amdgcn_cvt_pk_f32_fp8((int)(QV).y, true);     \
        acc[0] += es0 * p0.x; acc[1] += es1 * p0.y;                        \
        acc[2] += es2 * p1.x; acc[3] += es3 * p1.y;                        \
        acc[4] += es0 * p2.x; acc[5] += es1 * p2.y;                        \
        acc[6] += es2 * p3.x; acc[7] += es3 * p3.y;                        \
    }

    {   // self contribution
        float av = b2f(a_sb[nd * HEADS + h0]);
        uint2 qv = xv[(size_t)nd * 64 + ln];
        EDGE_BODY(av, qv)
    }

    int i = 0;
    for (; i + 8 <= cnt; i += 8) {
        int sv[8];
        #pragma unroll
        for (int k = 0; k < 8; ++k) sv[k] = csr[beg + i + k];
        float av[8];
        #pragma unroll
        for (int k = 0; k < 8; ++k) av[k] = b2f(a_sb[sv[k] * HEADS + h0]);
        uint2 qv[8];
        #pragma unroll
        for (int k = 0; k < 8; ++k) qv[k] = xv[(size_t)sv[k] * 64 + ln];
        #pragma unroll
        for (int k = 0; k < 8; ++k) EDGE_BODY(av[k], qv[k])
    }
    for (; i < cnt; ++i) {
        int s = csr[beg + i];
        float av = b2f(a_sb[s * HEADS + h0]);
        uint2 qv = xv[(size_t)s * 64 + ln];
        EDGE_BODY(av, qv)
    }
    #undef EDGE_BODY

    float inv = 1.f / (denom + 1e-16f);
    float iv0 = __shfl(inv, base + 0, 64);
    float iv1 = __shfl(inv, base + 1, 64);
    float iv2 = __shfl(inv, base + 2, 64);
    float iv3 = __shfl(inv, base + 3, 64);
    acc[0] *= iv0; acc[1] *= iv1; acc[2] *= iv2; acc[3] *= iv3;
    acc[4] *= iv0; acc[5] *= iv1; acc[6] *= iv2; acc[7] *= iv3;

    #pragma unroll
    for (int mask = 8; mask <= 32; mask <<= 1) {
        #pragma unroll
        for (int j = 0; j < 8; ++j) acc[j] += __shfl_xor(acc[j], mask, 64);
    }
    if (ln < 8) {
        #pragma unroll
        for (int p = 0; p < 2; ++p) {
            int c = 2 * ln + p;
            float o = (acc[p * 4] + acc[p * 4 + 1] + acc[p * 4 + 2] + acc[p * 4 + 3])
                      * (1.0f / HEADS) + bias[c];
            out[(size_t)nd * CDIM + c] = o > 0.f ? o : expm1f(o);
        }
    }
}

// x1 = elu(x @ w1t + b1); fp32 x, inline bf16 cast; wave = 64 rows x 64 cols
__global__ void k_mlp1(const float* __restrict__ x, const unsigned short* __restrict__ w1t,
                       const float* __restrict__ bb1, unsigned short* __restrict__ x1) {
    int wave = blockIdx.x * 4 + (threadIdx.x >> 6);
    if (wave >= 782) return;
    int lane = threadIdx.x & 63;
    int r = lane & 15, quad = lane >> 4;
    int row0 = wave * 64;

    f32x4 acc[4][4] = {};
    #pragma unroll
    for (int kc = 0; kc < 8; ++kc) {
        bf16x8 a[4];
        #pragma unroll
        for (int sub = 0; sub < 4; ++sub) {
            union { unsigned short u[8]; bf16x8 v; } ac;
            if (row0 + sub * 16 < NNODES) {    // sub-base mult of 16; rows <= 49999
                const float* p = x + (size_t)(row0 + sub * 16 + r) * DIN + kc * 32 + quad * 8;
                float4 a0 = *(const float4*)p;
                float4 a1 = *(const float4*)(p + 4);
                ac.u[0] = f2b(a0.x); ac.u[1] = f2b(a0.y); ac.u[2] = f2b(a0.z); ac.u[3] = f2b(a0.w);
                ac.u[4] = f2b(a1.x); ac.u[5] = f2b(a1.y); ac.u[6] = f2b(a1.z); ac.u[7] = f2b(a1.w);
            } else {
                #pragma unroll
                for (int j = 0; j < 8; ++j) ac.u[j] = 0;
            }
            a[sub] = ac.v;
        }
        #pragma unroll
        for (int t = 0; t < 4; ++t) {
            int col = t * 16 + r;
            bf16x8 b = *(const bf16x8*)(w1t + (size_t)col * DIN + kc * 32 + quad * 8);
            #pragma unroll
            for (int sub = 0; sub < 4; ++sub)
                acc[sub][t] = __builtin_amdgcn_mfma_f32_16x16x32_bf16(a[sub], b, acc[sub][t], 0, 0, 0);
        }
    }
    #pragma unroll
    for (int sub = 0; sub < 4; ++sub) {
        #pragma unroll
        for (int t = 0; t < 4; ++t) {
            int col = t * 16 + r;
            float bv = bb1[col];
            #pragma unroll
            for (int j = 0; j < 4; ++j) {
                int row = row0 + sub * 16 + quad * 4 + j;
                if (row < NNODES) {
                    float v = acc[sub][t][j] + bv;
                    v = v > 0.f ? v : expm1f(v);
                    x1[(size_t)row * 64 + col] = f2b(v);
                }
            }
        }
    }
}

// out = elu(x1 @ w2t + b2); wave = 16 rows x 16 cols; 3125 active waves
__global__ void k_mlp2(const unsigned short* __restrict__ x1,
                       const unsigned short* __restrict__ w2t,
                       const float* __restrict__ bb2, float* __restrict__ out) {
    int wave = blockIdx.x * 4 + (threadIdx.x >> 6);
    if (wave >= 3125) return;
    int lane = threadIdx.x & 63;
    int r = lane & 15, quad = lane >> 4;

    f32x4 acc = {};
    #pragma unroll
    for (int kc = 0; kc < 2; ++kc) {
        bf16x8 a = *(const bf16x8*)(x1 + (size_t)(wave * 16 + r) * 64 + kc * 32 + quad * 8);
        bf16x8 b = *(const bf16x8*)(w2t + (size_t)r * 64 + kc * 32 + quad * 8);
        acc = __builtin_amdgcn_mfma_f32_16x16x32_bf16(a, b, acc, 0, 0, 0);
    }
    float bv = bb2[r];
    #pragma unroll
    for (int j = 0; j < 4; ++j) {
        int row = wave * 16 + quad * 4 + j;
        float v = acc[j] + bv;
        v = v > 0.f ? v : expm1f(v);
        out[(size_t)row * CDIM + r] = v;
    }
}

extern "C" void kernel_launch(void* const* d_in, const int* in_sizes, int n_in,
                              void* d_out, int out_size, void* d_ws, size_t ws_size,
                              hipStream_t stream) {
    const float* x  = (const float*)d_in[0];
    const int* ei   = (const int*)d_in[1];
    const float* W[2]    = {(const float*)d_in[2], (const float*)d_in[6]};
    const float* atS[2]  = {(const float*)d_in[3], (const float*)d_in[7]};
    const float* atD[2]  = {(const float*)d_in[4], (const float*)d_in[8]};
    const float* bias[2] = {(const float*)d_in[5], (const float*)d_in[9]};
    const float* w1 = (const float*)d_in[10];
    const float* b1 = (const float*)d_in[11];
    const float* w2 = (const float*)d_in[12];
    const float* b2 = (const float*)d_in[13];
    float* out = (float*)d_out;

    char* ws = (char*)d_ws;
    unsigned* xp8 = (unsigned*)(ws);                            // 25,600,000 B
    unsigned short* Wt1 = (unsigned short*)(ws + 25600000);     //    262,144 B
    unsigned short* Wt2 = (unsigned short*)(ws + 25862144);     //    262,144 B
    unsigned short* w1t = (unsigned short*)(ws + 26124288);     //     32,768 B
    unsigned short* w2t = (unsigned short*)(ws + 26157056);     //      2,048 B
    unsigned short* a_sb = (unsigned short*)(ws + 26159104);    //  3,200,000 B
    unsigned short* a_db = (unsigned short*)(ws + 29359104);    //  3,200,000 B
    unsigned short* x1   = (unsigned short*)(ws + 32559104);    //  6,400,000 B
    int* deg  = (int*)(ws + 38959104);                          //    200,000 B
    int* rs   = (int*)(ws + 39159104);                          //    200,000 B
    int* cur  = (int*)(ws + 39359104);                          //    200,000 B
    int* part = (int*)(ws + 39559104);                          //    200,000 B
    int* bsum = (int*)(ws + 39759104);                          //      1,024 B
    int* csr  = (int*)(ws + 39760128);                          //  3,200,000 B
    int* flag = (int*)(ws + 42960128);                          //          4 B

    const unsigned short* Wt[2] = {Wt1, Wt2};

    k_prep    <<<SCAN_B, 256, 0, stream>>>(ei, flag, deg);
    k_hist    <<<3125, 256, 0, stream>>>(ei, flag, deg);
    k_scan_blk<<<SCAN_B, 256, 0, stream>>>(deg, part, bsum);
    k_scan_top<<<1, 256, 0, stream>>>(bsum);
    k_scan_add<<<SCAN_B, 256, 0, stream>>>(part, bsum, rs, cur);
    k_scatter <<<3125, 256, 0, stream>>>(ei, flag, cur, csr);
    k_trW     <<<1104, 256, 0, stream>>>(W[0], W[1], w1, w2, Wt1, Wt2, w1t, w2t);

    for (int cv = 0; cv < 2; ++cv) {
        k_gemm_xp<<<782, 512, 0, stream>>>(x, Wt[cv], xp8);
        k_att    <<<12500, 256, 0, stream>>>(xp8, atS[cv], atD[cv], a_sb, a_db);
        k_conv   <<<12500, 256, 0, stream>>>(csr, rs, deg, xp8, a_sb, a_db,
                                             bias[cv], out + (size_t)cv * 800000);
    }
    k_mlp1<<<196, 256, 0, stream>>>(x, w1t, b1, x1);
    k_mlp2<<<782, 256, 0, stream>>>(x1, w2t, b2, out + 1600000);
}